// Round 5
// baseline (325.459 us; speedup 1.0000x reference)
//
#include <hip/hip_runtime.h>
#include <math.h>

// RWKV-6 fused recurrent WKV, chunked linear scan, SGPR-broadcast formulation.
// B=4, T=2048, H=16, N=64, fp32.
//
// Per (b,h):  S[i][j] <- d_t[i]*S[i][j] + k_t[i]*v_t[j]
//             o_t[j]  = sum_i r_i*S_ij  +  v_j * sruk,  sruk = sum_i r_i*u_i*k_i
//
// ROUND-4 LESSON: the LDS-broadcast variant issues 17 LDS ops per wave-t;
// at ~11 cyc each on the per-CU LDS pipe that's ~175us for K3 alone. All
// broadcast data (r,k,d rows) is wave-uniform when ONE wave owns all 64 j
// (lane = j, S[64] in VGPRs). Uniform loads of read-only __restrict__ arrays
// compile to s_load (SMEM pipe) -> zero LDS traffic in the hot loops.
//
// K0: stream pass. D = exp(-exp(w)); A_g[i] = exp(-sum_chunk exp(w));
//     SR[t] = sum_i r u k (the j-independent bonus term).
// K1: per chunk, recurrence from zero -> L_g[i][j]. lane=j, S[64] VGPR,
//     k/D rows via uniform (SMEM) loads. No LDS, no exp.
// K2: per (b,h,i,j): S0_{g+1} = A_g[i]*S0_g + L_g  (in place, L -> S0)
// K3: per chunk, recurrence from S0_g -> outputs. Adds r-row FMAs + SR.
//
// Register discipline (R3 lesson): (64,4) -> 128-reg budget. S[64]+~20 fits.
// K0 is tiny -> (64,8).

namespace {
constexpr int B = 4, T = 2048, H = 16, N = 64;
constexpr int BH = B * H;

__device__ __forceinline__ float wave_sum64(float x) {
#pragma unroll
    for (int m = 1; m < 64; m <<= 1) x += __shfl_xor(x, m, 64);
    return x;
}

// ---------------- K0: streaming precompute (lane = i) -----------------------
template<int TC>
__global__ __launch_bounds__(64, 8)
void k0_pre(const float* __restrict__ rp, const float* __restrict__ kp,
            const float* __restrict__ wp, const float* __restrict__ up,
            float* __restrict__ D, float* __restrict__ A,
            float* __restrict__ SR, int NGc)
{
    const int blk = blockIdx.x;            // bh*NGc + g
    const int g   = blk % NGc;
    const int bh  = blk / NGc;
    const int b   = bh / H, h = bh - b * H;
    const int l   = threadIdx.x;           // lane = i

    const float ul = up[h * N + l];
    const int stride = H * N;
    int base = ((b * T + g * TC) * H + h) * N;

    float es = 0.f;                        // sum of exp(w) over the chunk
#pragma unroll 1
    for (int tt = 0; tt < TC; ++tt) {
        const float rl = rp[base + l];
        const float kl = kp[base + l];
        const float wl = wp[base + l];
        const float e  = expf(wl);
        D[base + l] = expf(-e);            // per-step decay
        es += e;
        const float s = wave_sum64(rl * ul * kl);
        if (l == 0) SR[bh * T + g * TC + tt] = s;
        base += stride;
    }
    A[(bh * NGc + g) * N + l] = expf(-es); // chunk decay product, per i
}

// ---------------- K1: chunk-local recurrence from zero (lane = j) -----------
template<int TC>
__global__ __launch_bounds__(64, 4)
void k1_chunk_local(const float* __restrict__ kp, const float* __restrict__ vp,
                    const float* __restrict__ Dp, float* __restrict__ L, int NGc)
{
    const int blk = blockIdx.x;
    const int g   = blk % NGc;
    const int bh  = blk / NGc;
    const int b   = bh / H, h = bh - b * H;
    const int j   = threadIdx.x;

    float S[N];
#pragma unroll
    for (int i = 0; i < N; ++i) S[i] = 0.f;

    const int stride = H * N;
    int base = ((b * T + g * TC) * H + h) * N;

#pragma unroll 1
    for (int tt = 0; tt < TC; ++tt) {
        const float vj  = vp[base + j];    // per-lane vector load
        const int   row = base;            // wave-uniform row base
#pragma unroll
        for (int i = 0; i < N; ++i) {
            // kp[row+i], Dp[row+i] are wave-uniform -> SMEM (SGPR operands)
            S[i] = fmaf(Dp[row + i], S[i], kp[row + i] * vj);
        }
        base += stride;
    }

    const int cb = (bh * NGc + g) * (N * N) + j;
#pragma unroll
    for (int i = 0; i < N; ++i) L[cb + i * N] = S[i];   // coalesced over j
}

// ---------------- K2: inter-chunk scan, in place (L -> S0), float4 ----------
__global__ __launch_bounds__(256)
void k2_scan(float* __restrict__ L, const float* __restrict__ A, int NGr)
{
    const int tid = blockIdx.x * 256 + threadIdx.x;   // over BH*N*N/4
    const int j4 = tid & (N / 4 - 1);
    const int i  = (tid >> 4) & (N - 1);
    const int bh = tid >> 10;

    float4* L4 = (float4*)L;
    const int lstride = N * N / 4;
    int lidx = bh * NGr * lstride + i * (N / 4) + j4;
    int aidx = bh * NGr * N + i;

    float4 S = make_float4(0.f, 0.f, 0.f, 0.f);
    for (int g = 0; g < NGr; ++g) {
        const float4 l = L4[lidx];
        const float  a = A[aidx];
        L4[lidx] = S;                // state at START of chunk g
        S.x = fmaf(a, S.x, l.x);
        S.y = fmaf(a, S.y, l.y);
        S.z = fmaf(a, S.z, l.z);
        S.w = fmaf(a, S.w, l.w);
        lidx += lstride;
        aidx += N;
    }
}

// ---------------- K3: chunk recurrence with true init state -> outputs ------
// FAST=true: D/SR precomputed, S0 from K2. FAST=false: no-workspace sequential
// fallback (NGc=1, TC=T, zero init, inline exp + inline sruk).
template<int TC, bool FAST>
__global__ __launch_bounds__(64, 4)
void k3_chunk_out(const float* __restrict__ rp, const float* __restrict__ kp,
                  const float* __restrict__ vp, const float* __restrict__ wp,
                  const float* __restrict__ up,
                  const float* __restrict__ Dp, const float* __restrict__ SRp,
                  const float* __restrict__ S0,
                  float* __restrict__ out, int NGc)
{
    const int blk = blockIdx.x;
    const int g   = blk % NGc;
    const int bh  = blk / NGc;
    const int b   = bh / H, h = bh - b * H;
    const int j   = threadIdx.x;

    float S[N];
    if (FAST) {
        const int cb = (bh * NGc + g) * (N * N) + j;
#pragma unroll
        for (int i = 0; i < N; ++i) S[i] = S0[cb + i * N];
    } else {
#pragma unroll
        for (int i = 0; i < N; ++i) S[i] = 0.f;
    }

    const int stride = H * N;
    int base = ((b * T + g * TC) * H + h) * N;
    const int ubase = h * N;

#pragma unroll 1
    for (int tt = 0; tt < TC; ++tt) {
        const float vj  = vp[base + j];    // per-lane vector load
        const int   row = base;            // wave-uniform row base

        float sr;
        if (FAST) sr = SRp[bh * T + g * TC + tt];   // uniform scalar
        float o0 = 0.f, o1 = 0.f, o2 = 0.f, o3 = 0.f;
        float sk = 0.f;
#pragma unroll
        for (int i = 0; i < N; ++i) {
            // rp/kp/Dp rows wave-uniform -> SMEM (SGPR operands, 1 per VALU op)
            const float ki = kp[row + i];
            const float di = FAST ? Dp[row + i] : expf(-expf(wp[row + i]));
            if (!FAST) sk = fmaf(rp[row + i] * up[ubase + i], ki, sk);
            if ((i & 3) == 0)      o0 = fmaf(rp[row + i], S[i], o0);
            else if ((i & 3) == 1) o1 = fmaf(rp[row + i], S[i], o1);
            else if ((i & 3) == 2) o2 = fmaf(rp[row + i], S[i], o2);
            else                   o3 = fmaf(rp[row + i], S[i], o3);
            S[i] = fmaf(di, S[i], ki * vj);
        }
        if (!FAST) sr = sk;
        out[base + j] = fmaf(sr, vj, (o0 + o1) + (o2 + o3));
        base += stride;
    }
}

} // anon namespace

extern "C" void kernel_launch(void* const* d_in, const int* in_sizes, int n_in,
                              void* d_out, int out_size, void* d_ws, size_t ws_size,
                              hipStream_t stream)
{
    const float* r = (const float*)d_in[0];
    const float* k = (const float*)d_in[1];
    const float* v = (const float*)d_in[2];
    const float* w = (const float*)d_in[3];
    const float* u = (const float*)d_in[4];
    float* out = (float*)d_out;

    const size_t d_elems  = (size_t)B * T * H * N;     // 8,388,608 (33.55 MB)
    const size_t sr_elems = (size_t)BH * T;            // 131,072   (0.52 MB)

    auto run = [&](auto tc_tag, int NG) {
        constexpr int TC = decltype(tc_tag)::value;
        const size_t l_elems = (size_t)BH * NG * N * N;
        const size_t a_elems = (size_t)BH * NG * N;
        float* L  = (float*)d_ws;
        float* A  = L + l_elems;
        float* SR = A + a_elems;
        float* D  = SR + sr_elems;
        k0_pre<TC><<<BH * NG, 64, 0, stream>>>(r, k, w, u, D, A, SR, NG);
        k1_chunk_local<TC><<<BH * NG, 64, 0, stream>>>(k, v, D, L, NG);
        k2_scan<<<(BH * N * N / 4) / 256, 256, 0, stream>>>(L, A, NG);
        k3_chunk_out<TC, true><<<BH * NG, 64, 0, stream>>>(r, k, v, w, u, D, SR,
                                                           L, out, NG);
    };

    auto ws_need = [&](int NG) {
        return ((size_t)BH * NG * N * N + (size_t)BH * NG * N
                + sr_elems + d_elems) * sizeof(float);
    };

    if (ws_size >= ws_need(64)) {            // ~102.2 MB
        run(std::integral_constant<int, T / 64>{}, 64);
    } else if (ws_size >= ws_need(32)) {     // ~68.16 MB (proven available in R2)
        run(std::integral_constant<int, T / 32>{}, 32);
    } else {
        // No-workspace fallback: fully sequential per (b,h). Slow but correct.
        k3_chunk_out<T, false><<<BH, 64, 0, stream>>>(r, k, v, w, u,
                                                      nullptr, nullptr, nullptr,
                                                      out, 1);
    }
}

// Round 6
// 277.596 us; speedup vs baseline: 1.1724x; 1.1724x over previous
//
#include <hip/hip_runtime.h>
#include <math.h>

// RWKV-6 fused recurrent WKV, chunked linear scan, SGPR-broadcast formulation.
// B=4, T=2048, H=16, N=64, fp32.
//
// Per (b,h):  S[i][j] <- d_t[i]*S[i][j] + k_t[i]*v_t[j]
//             o_t[j]  = sum_i r_i*S_ij  +  v_j * sruk,  sruk = sum_i r_i*u_i*k_i
//
// R4 LESSON: LDS-broadcast costs 17 LDS ops/wave-t -> LDS-pipe bound (175us).
//   Fix: lane=j, S[64]/lane; r/k/d rows are wave-uniform -> s_load (SMEM pipe),
//   zero LDS in hot loops (R5 confirmed: SGPR=112, LDS=0, conflicts=0).
// R5 LESSON: S[64] at the 128-reg tier ((64,4)) spills ~265MB to scratch
//   (VGPR=64 + WRITE_SIZE 299MB). S[64]+SMEM temps needs the 256-reg tier:
//   __launch_bounds__(64,2). 2 waves/SIMD is fine -- the unrolled 192-FMA
//   body has plenty of in-wave ILP.
//
// K0: stream pass. D = exp(-exp(w)); A_g[i] = exp(-sum_chunk exp(w));
//     SR[t] = sum_i r u k.
// K1: per chunk, recurrence from zero -> L_g[i][j]. No LDS, no exp.
// K2: per (b,h,i,j): S0_{g+1} = A_g[i]*S0_g + L_g  (in place, L -> S0)
// K3: per chunk, recurrence from S0_g -> outputs.

namespace {
constexpr int B = 4, T = 2048, H = 16, N = 64;
constexpr int BH = B * H;
constexpr int NG = 32;           // chunks per (b,h): grid 2048 = 8 blocks/CU
constexpr int TC = T / NG;       // 64 steps per chunk

__device__ __forceinline__ float wave_sum64(float x) {
#pragma unroll
    for (int m = 1; m < 64; m <<= 1) x += __shfl_xor(x, m, 64);
    return x;
}

// ---------------- K0: streaming precompute (lane = i) -----------------------
__global__ __launch_bounds__(64, 8)
void k0_pre(const float* __restrict__ rp, const float* __restrict__ kp,
            const float* __restrict__ wp, const float* __restrict__ up,
            float* __restrict__ D, float* __restrict__ A,
            float* __restrict__ SR)
{
    const int blk = blockIdx.x;            // bh*NG + g
    const int g   = blk % NG;
    const int bh  = blk / NG;
    const int b   = bh / H, h = bh - b * H;
    const int l   = threadIdx.x;           // lane = i

    const float ul = up[h * N + l];
    const int stride = H * N;
    int base = ((b * T + g * TC) * H + h) * N;

    float es = 0.f;                        // sum of exp(w) over the chunk
#pragma unroll 1
    for (int tt = 0; tt < TC; ++tt) {
        const float rl = rp[base + l];
        const float kl = kp[base + l];
        const float wl = wp[base + l];
        const float e  = expf(wl);
        D[base + l] = expf(-e);            // per-step decay
        es += e;
        const float s = wave_sum64(rl * ul * kl);
        if (l == 0) SR[bh * T + g * TC + tt] = s;
        base += stride;
    }
    A[(bh * NG + g) * N + l] = expf(-es);  // chunk decay product, per i
}

// ---------------- K1: chunk-local recurrence from zero (lane = j) -----------
__global__ __launch_bounds__(64, 2)
void k1_chunk_local(const float* __restrict__ kp, const float* __restrict__ vp,
                    const float* __restrict__ Dp, float* __restrict__ L)
{
    const int blk = blockIdx.x;
    const int g   = blk % NG;
    const int bh  = blk / NG;
    const int b   = bh / H, h = bh - b * H;
    const int j   = threadIdx.x;

    float S[N];
#pragma unroll
    for (int i = 0; i < N; ++i) S[i] = 0.f;

    const int stride = H * N;
    int base = ((b * T + g * TC) * H + h) * N;

#pragma unroll 1
    for (int tt = 0; tt < TC; ++tt) {
        const float vj = vp[base + j];     // per-lane vector load
        const int row  = base;             // wave-uniform row base -> s_load
#pragma unroll
        for (int i = 0; i < N; ++i) {
            S[i] = fmaf(Dp[row + i], S[i], kp[row + i] * vj);
        }
        base += stride;
    }

    const int cb = (bh * NG + g) * (N * N) + j;
#pragma unroll
    for (int i = 0; i < N; ++i) L[cb + i * N] = S[i];   // coalesced over j
}

// ---------------- K2: inter-chunk scan, in place (L -> S0), float4 ----------
__global__ __launch_bounds__(256)
void k2_scan(float* __restrict__ L, const float* __restrict__ A)
{
    const int tid = blockIdx.x * 256 + threadIdx.x;   // over BH*N*N/4
    const int j4 = tid & (N / 4 - 1);
    const int i  = (tid >> 4) & (N - 1);
    const int bh = tid >> 10;

    float4* L4 = (float4*)L;
    const int lstride = N * N / 4;
    int lidx = bh * NG * lstride + i * (N / 4) + j4;
    int aidx = bh * NG * N + i;

    float4 S = make_float4(0.f, 0.f, 0.f, 0.f);
    for (int g = 0; g < NG; ++g) {
        const float4 l = L4[lidx];
        const float  a = A[aidx];
        L4[lidx] = S;                // state at START of chunk g
        S.x = fmaf(a, S.x, l.x);
        S.y = fmaf(a, S.y, l.y);
        S.z = fmaf(a, S.z, l.z);
        S.w = fmaf(a, S.w, l.w);
        lidx += lstride;
        aidx += N;
    }
}

// ---------------- K3: chunk recurrence with true init state -> outputs ------
// FAST=true: D/SR precomputed, S0 from K2. FAST=false: no-workspace sequential
// fallback (one chunk = whole T, zero init, inline exp + inline sruk).
template<int STEPS, int NGc, bool FAST>
__global__ __launch_bounds__(64, 2)
void k3_chunk_out(const float* __restrict__ rp, const float* __restrict__ kp,
                  const float* __restrict__ vp, const float* __restrict__ wp,
                  const float* __restrict__ up,
                  const float* __restrict__ Dp, const float* __restrict__ SRp,
                  const float* __restrict__ S0,
                  float* __restrict__ out)
{
    const int blk = blockIdx.x;
    const int g   = blk % NGc;
    const int bh  = blk / NGc;
    const int b   = bh / H, h = bh - b * H;
    const int j   = threadIdx.x;

    float S[N];
    if (FAST) {
        const int cb = (bh * NGc + g) * (N * N) + j;
#pragma unroll
        for (int i = 0; i < N; ++i) S[i] = S0[cb + i * N];
    } else {
#pragma unroll
        for (int i = 0; i < N; ++i) S[i] = 0.f;
    }

    const int stride = H * N;
    int base = ((b * T + g * STEPS) * H + h) * N;
    const int ubase = h * N;

#pragma unroll 1
    for (int tt = 0; tt < STEPS; ++tt) {
        const float vj = vp[base + j];     // per-lane vector load
        const int row  = base;             // wave-uniform row base -> s_load

        float sr = FAST ? SRp[bh * T + g * STEPS + tt] : 0.f;
        float o0 = 0.f, o1 = 0.f;
#pragma unroll
        for (int i = 0; i < N; ++i) {
            // rp/kp/Dp rows wave-uniform -> SGPR operands (1 per VALU op)
            const float ki = kp[row + i];
            const float di = FAST ? Dp[row + i] : expf(-expf(wp[row + i]));
            const float ri = rp[row + i];
            if (!FAST) sr = fmaf(ri * up[ubase + i], ki, sr);
            if (i & 1) o1 = fmaf(ri, S[i], o1);
            else       o0 = fmaf(ri, S[i], o0);
            S[i] = fmaf(di, S[i], ki * vj);
        }
        out[base + j] = fmaf(sr, vj, o0 + o1);
        base += stride;
    }
}

} // anon namespace

extern "C" void kernel_launch(void* const* d_in, const int* in_sizes, int n_in,
                              void* d_out, int out_size, void* d_ws, size_t ws_size,
                              hipStream_t stream)
{
    const float* r = (const float*)d_in[0];
    const float* k = (const float*)d_in[1];
    const float* v = (const float*)d_in[2];
    const float* w = (const float*)d_in[3];
    const float* u = (const float*)d_in[4];
    float* out = (float*)d_out;

    const size_t l_elems  = (size_t)BH * NG * N * N;   // 8,388,608  (33.55 MB)
    const size_t a_elems  = (size_t)BH * NG * N;       // 131,072    (0.52 MB)
    const size_t sr_elems = (size_t)BH * T;            // 131,072    (0.52 MB)
    const size_t d_elems  = (size_t)B * T * H * N;     // 8,388,608  (33.55 MB)
    const size_t ws_need  = (l_elems + a_elems + sr_elems + d_elems) * sizeof(float);
    // ~68.2 MB -- proven available in round 2.

    if (ws_size >= ws_need) {
        float* L  = (float*)d_ws;
        float* A  = L + l_elems;
        float* SR = A + a_elems;
        float* D  = SR + sr_elems;
        k0_pre<<<BH * NG, 64, 0, stream>>>(r, k, w, u, D, A, SR);
        k1_chunk_local<<<BH * NG, 64, 0, stream>>>(k, v, D, L);
        k2_scan<<<(BH * N * N / 4) / 256, 256, 0, stream>>>(L, A);
        k3_chunk_out<TC, NG, true><<<BH * NG, 64, 0, stream>>>(
            r, k, v, w, u, D, SR, L, out);
    } else {
        // No-workspace fallback: fully sequential per (b,h). Slow but correct.
        k3_chunk_out<T, 1, false><<<BH, 64, 0, stream>>>(
            r, k, v, w, u, nullptr, nullptr, nullptr, out);
    }
}

// Round 7
// 75.566 us; speedup vs baseline: 4.3069x; 3.6735x over previous
//
#include <hip/hip_runtime.h>
#include <math.h>

// RWKV-6 fused recurrent WKV — chunked linear scan, MFMA formulation.
// B=4, T=2048, H=16, N=64, fp32 in/out; bf16 MFMA operands, fp32 accum.
//
// Chunk TC=64 per workgroup (bh,g), 4 waves, wave w owns t-band [16w,16w+16).
// A[t,s] = sum_i r_t,i k_s,i exp(-(c[t]-c[s+1])), c = prefix of exp(w).
// Dyadic-safe factorization: boundary b(t,s) = (t>>l)<<l with l = msb(s^t):
//   A_l = (r*exp(-(c[t]-c[b]))) @ (k*exp(-(c[b]-c[s+1])))^T, all exponents <= 0.
// Levels 0-3 + u-diag: inside 16x16 diagonal tiles (masked per element).
// Level 4: whole tiles (1,0),(3,2). Level 5: whole tiles (2,*),(3,0),(3,1).
// o = R~0 @ S0 + A @ V;  L_g = K~end^T @ V  (feeds unchanged K2 scan).
//
// R2/R4/R6 lesson: per-t-step operand broadcast (LDS pipe 17 ops/t, or SMEM
// at 4 lgkmcnt(0) drains/t vs 102-SGPR file) is the wall. MFMA's crossbar
// broadcasts in hardware.

namespace {
constexpr int B = 4, T = 2048, H = 16, N = 64;
constexpr int BH = B * H;
constexpr int NG = 32;           // chunks per (b,h)
constexpr int TC = 64;           // steps per chunk

typedef __attribute__((ext_vector_type(8))) short s8v;   // 8 bf16 (guide idiom)
typedef __attribute__((ext_vector_type(4))) float f4v;

#define MFMA16(a, b, c) __builtin_amdgcn_mfma_f32_16x16x32_bf16((a), (b), (c), 0, 0, 0)

__device__ __forceinline__ unsigned short to_bf16(float f) {
    union { float f; unsigned u; } x; x.f = f;
    unsigned r = x.u + 0x7FFFu + ((x.u >> 16) & 1u);   // RNE
    return (unsigned short)(r >> 16);
}

// XOR-swizzled element index for [64][64] bf16 LDS tiles (16B-chunk swizzle):
// breaks the 16-way bank conflict of stride-128B ds_read_b128 column slices.
__device__ __forceinline__ int sw(int row, int col) {
    return row * 64 + (col ^ ((row & 7) << 3));
}

// MFMA fragment load (A-op from [m][k] layout, B-op from [n][k] layout):
// lane l -> row (l&15), k-slice 8*(l>>4). 8 contiguous bf16 = ds_read_b128.
__device__ __forceinline__ s8v frag8(const unsigned short* buf, int row_base, int k_base) {
    const int l = threadIdx.x & 63;
    return *(const s8v*)&buf[sw(row_base + (l & 15), k_base + 8 * (l >> 4))];
}

// ---------------- K1/K3 merged: PHASE 0 = local states, PHASE 1 = outputs ---
template<int PHASE>
__global__ __launch_bounds__(256, 4)
void k13(const float* __restrict__ rp, const float* __restrict__ kp,
         const float* __restrict__ vp, const float* __restrict__ wp,
         const float* __restrict__ up,
         const float* __restrict__ S0g,   // PHASE1: scanned chunk-start states
         float* __restrict__ Lg, float* __restrict__ Ag,   // PHASE0 outputs
         float* __restrict__ out)
{
    __shared__ unsigned short sA[64 * 64];   // A-operand staging [t][i] (or KT [i][t])
    __shared__ unsigned short sB[64 * 64];   // B-operand staging [s][i]
    __shared__ unsigned short sVT[64 * 64];  // V transposed [j][t]
    __shared__ unsigned short sST[64 * 64];  // S0 transposed [j][i] (PHASE1)
    __shared__ unsigned short sAm[64 * 64];  // A matrix bf16 [t][s] (PHASE1)
    __shared__ float spans[4 * 64];

    const int blk = blockIdx.x;
    const int g   = blk & (NG - 1);
    const int bh  = blk / NG;
    const int b   = bh / H, h = bh - b * H;
    const int wv  = threadIdx.x >> 6;        // wave 0..3, owns t-band [16wv,+16)
    const int ln  = threadIdx.x & 63;        // lane: i (prep) / frag lane (GEMM)

    const int stride = H * N;
    const int base_w = ((b * T + g * TC + wv * 16) * H + h) * N + ln;
    const int cb = (bh * NG + g) * (N * N);

    // ---- P1: load rows, cum prefix, stage V^T (and S0^T) -------------------
    float ci[16];                            // inclusive prefix of E = exp(w)
    float k_[16], r_[16];
    {
        float run = 0.f;
#pragma unroll
        for (int tt = 0; tt < 16; ++tt) {
            const int a = base_w + tt * stride;
            run += __expf(wp[a]);
            ci[tt] = run;
            k_[tt] = kp[a];
            if (PHASE == 1) r_[tt] = rp[a];
        }
        spans[wv * 64 + ln] = run;
    }
#pragma unroll
    for (int half = 0; half < 2; ++half) {   // V^T: row j=ln, cols t (own band)
        s8v pk;
#pragma unroll
        for (int e = 0; e < 8; ++e)
            pk[e] = (short)to_bf16(vp[base_w + (half * 8 + e) * stride]);
        *(s8v*)&sVT[sw(ln, wv * 16 + half * 8)] = pk;
    }
    if (PHASE == 1) {
#pragma unroll
        for (int half = 0; half < 2; ++half) {  // S0^T: row j=ln, cols i
            s8v pk;
#pragma unroll
            for (int e = 0; e < 8; ++e)
                pk[e] = (short)to_bf16(S0g[cb + (wv * 16 + half * 8 + e) * 64 + ln]);
            *(s8v*)&sST[sw(ln, wv * 16 + half * 8)] = pk;
        }
    }
    __syncthreads();
    const float sp0 = spans[0 * 64 + ln], sp1 = spans[1 * 64 + ln];
    const float sp2 = spans[2 * 64 + ln], sp3 = spans[3 * 64 + ln];
    const float offW = (wv > 0 ? sp0 : 0.f) + (wv > 1 ? sp1 : 0.f) + (wv > 2 ? sp2 : 0.f);
    const float ctot = sp0 + sp1 + sp2 + sp3;

    if (PHASE == 0) {
        // ---- K~end^T staging into sA as [i=ln][t] --------------------------
        s8v p0, p1;
#pragma unroll
        for (int tt = 0; tt < 16; ++tt) {
            const unsigned short v16 =
                to_bf16(k_[tt] * __expf(-(ctot - (offW + ci[tt]))));
            if (tt < 8) p0[tt] = (short)v16; else p1[tt - 8] = (short)v16;
        }
        *(s8v*)&sA[sw(ln, wv * 16)]     = p0;
        *(s8v*)&sA[sw(ln, wv * 16 + 8)] = p1;
        __syncthreads();
        // ---- L[i][j] = sum_t KT[i][t] V[t][j]; wave owns i-band ------------
#pragma unroll
        for (int jb = 0; jb < 4; ++jb) {
            f4v acc = {0.f, 0.f, 0.f, 0.f};
            acc = MFMA16(frag8(sA, wv * 16, 0),  frag8(sVT, jb * 16, 0),  acc);
            acc = MFMA16(frag8(sA, wv * 16, 32), frag8(sVT, jb * 16, 32), acc);
#pragma unroll
            for (int q = 0; q < 4; ++q) {
                const int i = wv * 16 + (ln >> 4) * 4 + q;
                Lg[cb + i * 64 + jb * 16 + (ln & 15)] = acc[q];
            }
        }
        if (wv == 0) Ag[(bh * NG + g) * 64 + ln] = __expf(-ctot);
        return;
    }

    // ======================= PHASE 1: outputs ==============================
    const float uln = up[h * 64 + ln];

    // ---- diag tile (wv,wv): levels 0..3 masked + u-diag --------------------
    f4v accD = {0.f, 0.f, 0.f, 0.f};
#pragma unroll
    for (int L = 0; L < 4; ++L) {
#pragma unroll
        for (int tt = 0; tt < 16; ++tt) {
            const int btl = (tt >> L) << L;          // floor boundary (local)
            const int bsl = btl + (1 << L);          // ceil boundary (local)
            const float cT  = (tt == 0) ? 0.f : ci[tt - 1];
            const float cBt = (btl == 0) ? 0.f : ci[btl - 1];
            const float cBs = ci[bsl - 1];
            sA[sw(wv * 16 + tt, ln)] = to_bf16(r_[tt] * __expf(-(cT - cBt)));
            sB[sw(wv * 16 + tt, ln)] = to_bf16(k_[tt] * __expf(-(cBs - ci[tt])));
        }
        f4v tmp = {0.f, 0.f, 0.f, 0.f};
        tmp = MFMA16(frag8(sA, wv * 16, 0),  frag8(sB, wv * 16, 0),  tmp);
        tmp = MFMA16(frag8(sA, wv * 16, 32), frag8(sB, wv * 16, 32), tmp);
        const int cc = ln & 15;
#pragma unroll
        for (int q = 0; q < 4; ++q) {
            const int tt = (ln >> 4) * 4 + q;
            if (((tt >> L) == ((cc >> L) + 1)) && (((tt >> L) & 1) != 0))
                accD[q] += tmp[q];
        }
    }
    {   // u-diag "level": A[t][t] = sum_i r u k
#pragma unroll
        for (int tt = 0; tt < 16; ++tt) {
            sA[sw(wv * 16 + tt, ln)] = to_bf16(r_[tt] * uln);
            sB[sw(wv * 16 + tt, ln)] = to_bf16(k_[tt]);
        }
        f4v tmp = {0.f, 0.f, 0.f, 0.f};
        tmp = MFMA16(frag8(sA, wv * 16, 0),  frag8(sB, wv * 16, 0),  tmp);
        tmp = MFMA16(frag8(sA, wv * 16, 32), frag8(sB, wv * 16, 32), tmp);
        const int cc = ln & 15;
#pragma unroll
        for (int q = 0; q < 4; ++q) {
            const int tt = (ln >> 4) * 4 + q;
            if (tt == cc) accD[q] += tmp[q];
        }
    }

    // ---- level 4: whole tiles (1,0),(3,2); refs = own band start/end -------
#pragma unroll
    for (int tt = 0; tt < 16; ++tt) {
        const float cT = (tt == 0) ? 0.f : ci[tt - 1];
        sA[sw(wv * 16 + tt, ln)] = to_bf16(r_[tt] * __expf(-cT));
        sB[sw(wv * 16 + tt, ln)] = to_bf16(k_[tt] * __expf(-(ci[15] - ci[tt])));
    }
    __syncthreads();
    f4v accL4 = {0.f, 0.f, 0.f, 0.f};
    if (wv == 1 || wv == 3) {
        accL4 = MFMA16(frag8(sA, wv * 16, 0),  frag8(sB, (wv - 1) * 16, 0),  accL4);
        accL4 = MFMA16(frag8(sA, wv * 16, 32), frag8(sB, (wv - 1) * 16, 32), accL4);
    }
    __syncthreads();

    // ---- level 5: tiles (2,0),(2,1),(3,0),(3,1); refs at c[32] -------------
#pragma unroll
    for (int tt = 0; tt < 16; ++tt) {
        if (wv >= 2) {
            const float cT = (tt == 0) ? 0.f : ci[tt - 1];
            const float d  = (wv == 2) ? cT : (cT + sp2);
            sA[sw(wv * 16 + tt, ln)] = to_bf16(r_[tt] * __expf(-d));
        } else {
            const float d = (wv == 0) ? (sp0 + sp1 - ci[tt]) : (sp1 - ci[tt]);
            sB[sw(wv * 16 + tt, ln)] = to_bf16(k_[tt] * __expf(-d));
        }
    }
    __syncthreads();
    f4v acc50 = {0.f, 0.f, 0.f, 0.f}, acc51 = {0.f, 0.f, 0.f, 0.f};
    if (wv >= 2) {
        acc50 = MFMA16(frag8(sA, wv * 16, 0),  frag8(sB, 0, 0),   acc50);
        acc50 = MFMA16(frag8(sA, wv * 16, 32), frag8(sB, 0, 32),  acc50);
        acc51 = MFMA16(frag8(sA, wv * 16, 0),  frag8(sB, 16, 0),  acc51);
        acc51 = MFMA16(frag8(sA, wv * 16, 32), frag8(sB, 16, 32), acc51);
    }
    // (no barrier: R~0 prep below writes only own sA rows; L5 GEMM reads own
    //  sA rows + sB bands 0/1 which are not rewritten)

    // ---- R~0 (chunk-start ref) + O_inter = R~0 @ S0 ------------------------
#pragma unroll
    for (int tt = 0; tt < 16; ++tt) {
        const float cT = (tt == 0) ? 0.f : ci[tt - 1];
        sA[sw(wv * 16 + tt, ln)] = to_bf16(r_[tt] * __expf(-(offW + cT)));
    }
    f4v accO[4];
#pragma unroll
    for (int jb = 0; jb < 4; ++jb) {
        f4v a = {0.f, 0.f, 0.f, 0.f};
        a = MFMA16(frag8(sA, wv * 16, 0),  frag8(sST, jb * 16, 0),  a);
        a = MFMA16(frag8(sA, wv * 16, 32), frag8(sST, jb * 16, 32), a);
        accO[jb] = a;
    }

    // ---- materialize A (bf16, swizzled) into sAm; zero (0,1),(2,3) ---------
    {
        const int cc = ln & 15;
#pragma unroll
        for (int q = 0; q < 4; ++q) {
            const int tt = (ln >> 4) * 4 + q;
            sAm[sw(wv * 16 + tt, wv * 16 + cc)] = to_bf16(accD[q]);
        }
        if (wv == 1 || wv == 3) {
#pragma unroll
            for (int q = 0; q < 4; ++q) {
                const int tt = (ln >> 4) * 4 + q;
                sAm[sw(wv * 16 + tt, (wv - 1) * 16 + cc)] = to_bf16(accL4[q]);
            }
        }
        if (wv >= 2) {
#pragma unroll
            for (int q = 0; q < 4; ++q) {
                const int tt = (ln >> 4) * 4 + q;
                sAm[sw(wv * 16 + tt, cc)]      = to_bf16(acc50[q]);
                sAm[sw(wv * 16 + tt, 16 + cc)] = to_bf16(acc51[q]);
            }
        }
        if (wv == 0 || wv == 2) {    // zero upper-adjacent tile for K32 pairing
#pragma unroll
            for (int q = 0; q < 4; ++q) {
                const int tt = (ln >> 4) * 4 + q;
                sAm[sw(wv * 16 + tt, (wv + 1) * 16 + cc)] = 0;
            }
        }
    }
    // own-band rows only are read below -> no barrier needed, but sVT is
    // cross-wave (synced at P1). A@V:
#pragma unroll
    for (int jb = 0; jb < 4; ++jb) {
        f4v a = accO[jb];
        a = MFMA16(frag8(sAm, wv * 16, 0), frag8(sVT, jb * 16, 0), a);
        if (wv >= 2)
            a = MFMA16(frag8(sAm, wv * 16, 32), frag8(sVT, jb * 16, 32), a);
#pragma unroll
        for (int q = 0; q < 4; ++q) {
            const int t = g * TC + wv * 16 + (ln >> 4) * 4 + q;
            out[((b * T + t) * H + h) * N + jb * 16 + (ln & 15)] = a[q];
        }
    }
}

// ---------------- K2: inter-chunk scan, in place (L -> S0), float4 ----------
__global__ __launch_bounds__(256)
void k2_scan(float* __restrict__ L, const float* __restrict__ A)
{
    const int tid = blockIdx.x * 256 + threadIdx.x;
    const int j4 = tid & (N / 4 - 1);
    const int i  = (tid >> 4) & (N - 1);
    const int bh = tid >> 10;

    float4* L4 = (float4*)L;
    const int lstride = N * N / 4;
    int lidx = bh * NG * lstride + i * (N / 4) + j4;
    int aidx = bh * NG * N + i;

    float4 S = make_float4(0.f, 0.f, 0.f, 0.f);
    for (int g = 0; g < NG; ++g) {
        const float4 l = L4[lidx];
        const float  a = A[aidx];
        L4[lidx] = S;
        S.x = fmaf(a, S.x, l.x);
        S.y = fmaf(a, S.y, l.y);
        S.z = fmaf(a, S.z, l.z);
        S.w = fmaf(a, S.w, l.w);
        lidx += lstride;
        aidx += N;
    }
}

// ---------------- no-workspace fallback: sequential per (b,h) ---------------
__global__ __launch_bounds__(64, 2)
void k_seq(const float* __restrict__ rp, const float* __restrict__ kp,
           const float* __restrict__ vp, const float* __restrict__ wp,
           const float* __restrict__ up, float* __restrict__ out)
{
    const int bh = blockIdx.x;
    const int b = bh / H, h = bh - b * H;
    const int j = threadIdx.x;

    float S[N];
#pragma unroll
    for (int i = 0; i < N; ++i) S[i] = 0.f;

    const int stride = H * N;
    int base = ((b * T) * H + h) * N;
    const int ubase = h * N;

#pragma unroll 1
    for (int tt = 0; tt < T; ++tt) {
        const float vj = vp[base + j];
        const int row = base;
        float sr = 0.f, o0 = 0.f, o1 = 0.f;
#pragma unroll
        for (int i = 0; i < N; ++i) {
            const float ki = kp[row + i];
            const float di = __expf(-__expf(wp[row + i]));
            const float ri = rp[row + i];
            sr = fmaf(ri * up[ubase + i], ki, sr);
            if (i & 1) o1 = fmaf(ri, S[i], o1);
            else       o0 = fmaf(ri, S[i], o0);
            S[i] = fmaf(di, S[i], ki * vj);
        }
        out[base + j] = fmaf(sr, vj, o0 + o1);
        base += stride;
    }
}

} // anon namespace

extern "C" void kernel_launch(void* const* d_in, const int* in_sizes, int n_in,
                              void* d_out, int out_size, void* d_ws, size_t ws_size,
                              hipStream_t stream)
{
    const float* r = (const float*)d_in[0];
    const float* k = (const float*)d_in[1];
    const float* v = (const float*)d_in[2];
    const float* w = (const float*)d_in[3];
    const float* u = (const float*)d_in[4];
    float* out = (float*)d_out;

    const size_t l_elems = (size_t)BH * NG * N * N;   // 8,388,608
    const size_t a_elems = (size_t)BH * NG * N;       // 131,072
    const size_t ws_need = (l_elems + a_elems) * sizeof(float);  // ~34 MB

    if (ws_size >= ws_need) {
        float* L = (float*)d_ws;
        float* A = L + l_elems;
        k13<0><<<BH * NG, 256, 0, stream>>>(r, k, v, w, u, nullptr, L, A, nullptr);
        k2_scan<<<(BH * N * N / 4) / 256, 256, 0, stream>>>(L, A);
        k13<1><<<BH * NG, 256, 0, stream>>>(r, k, v, w, u, L, nullptr, nullptr, out);
    } else {
        k_seq<<<BH, 64, 0, stream>>>(r, k, v, w, u, out);
    }
}